// Round 5
// baseline (740.458 us; speedup 1.0000x reference)
//
#include <hip/hip_runtime.h>

// Problem constants (match reference)
#define NX_ 432
#define NY_ 496
#define C_  64
#define B_  4
#define CELLS_ (NX_ * NY_)            // 214272 cells per (bin, batch) canvas plane
#define PLANE_ ((size_t)CELLS_)       // c-plane stride in floats
#define BATCH_STRIDE_ ((size_t)C_ * CELLS_)        // 13,713,408 floats
#define BIN_STRIDE_   ((size_t)B_ * C_ * CELLS_)   // 54,853,632 floats
#define MAP_BIN_ ((size_t)B_ * CELLS_)             // map entries per bin

#define TCELLS_  216                  // cells per block tile; 214272/216 = 992 exact
#define NCHUNK_  992
#define TSTRIDE_ 217                  // padded LDS row stride (odd vs 32 banks)
#define TFLOATS_ (C_ * TCELLS_)       // 13824 output floats per block

// native clang vector types — accepted by __builtin_nontemporal_store
typedef float vfloat4 __attribute__((ext_vector_type(4)));
typedef int   vint4   __attribute__((ext_vector_type(4)));

// ---------------------------------------------------------------------------
// Kernel 1: scatter pillar index p into map[bin][b*CELLS + z + y*NX + x]
// coords layout per row: [b, z, y, x] int32. Cells are unique per sample.
// ---------------------------------------------------------------------------
__global__ __launch_bounds__(256) void scatter_idx_kernel(
    const int* __restrict__ coords0,
    const int* __restrict__ coords1,
    const int* __restrict__ coords2,
    int* __restrict__ map, int npil)
{
    const int bin = blockIdx.y;
    const int p = blockIdx.x * 256 + threadIdx.x;
    if (p >= npil) return;
    const int* coords = (bin == 0) ? coords0 : (bin == 1) ? coords1 : coords2;
    vint4 c = ((const vint4*)coords)[p];
    size_t idx = (size_t)bin * MAP_BIN_ + (size_t)c.x * CELLS_ + c.y + c.z * NX_ + c.w;
    map[idx] = p;
}

// ---------------------------------------------------------------------------
// Kernel 2: LDS-staged gather. Block = (bin, b, 216-cell chunk).
//  1. zero 64x217 LDS tile
//  2. load map (1 dword/thread), compact valid (cell,pillar) into LDS list
//  3. per valid entry: ONE wave reads the full pillar row coalesced
//     (lane = c, 256B, each row read exactly once per bin) and scatters
//     into the tile (stride 217 -> 2-way bank aliasing = free)
//  4. stream tile to global: ~13.5 nontemporal dwordx4 stores per thread
// Global VMEM per block ~ 3456 stores + 216 map loads + ~16 row loads:
// store-dominated, traffic = 658MB out + 49MB rows + 10MB map.
// ---------------------------------------------------------------------------
__global__ __launch_bounds__(256) void gather_lds_kernel(
    const float* __restrict__ pf0,
    const float* __restrict__ pf1,
    const float* __restrict__ pf2,
    const int* __restrict__ map,
    float* __restrict__ out)
{
    __shared__ float tile[C_ * TSTRIDE_];   // 55,552 B
    __shared__ unsigned list[256];
    __shared__ int cnt;

    const int chunk = blockIdx.x;   // 0..991
    const int b     = blockIdx.y;   // 0..3
    const int bin   = blockIdx.z;   // 0..2
    const int tid   = threadIdx.x;

    const float* __restrict__ pf = (bin == 0) ? pf0 : (bin == 1) ? pf1 : pf2;

    // Phase 1: zero the tile (13888 floats = 3472 float4)
    {
        vfloat4 z = {0.0f, 0.0f, 0.0f, 0.0f};
        vfloat4* t4 = (vfloat4*)tile;
        #pragma unroll
        for (int i = tid; i < (C_ * TSTRIDE_) / 4; i += 256) t4[i] = z;
    }
    if (tid == 0) cnt = 0;
    __syncthreads();

    // Phase 2: load map once, compact valid entries (~16 expected)
    if (tid < TCELLS_) {
        int p = map[(size_t)bin * MAP_BIN_ + (size_t)b * CELLS_
                    + (size_t)chunk * TCELLS_ + tid];
        if (p >= 0) {
            int pos = atomicAdd(&cnt, 1);
            list[pos] = ((unsigned)tid << 16) | (unsigned)p;   // p < 64000 < 2^16
        }
    }
    __syncthreads();

    // Phase 3: one wave per valid entry — coalesced full-row read, LDS scatter
    const int wave = tid >> 6, lane = tid & 63;
    const int n = cnt;
    for (int e = wave; e < n; e += 4) {
        unsigned ent = list[e];
        int cell = (int)(ent >> 16);
        int p    = (int)(ent & 0xFFFFu);
        tile[lane * TSTRIDE_ + cell] = pf[(size_t)p * C_ + lane];
    }
    __syncthreads();

    // Phase 4: stream tile to global, coalesced nontemporal float4 stores
    float* obase = out + (size_t)bin * BIN_STRIDE_ + (size_t)b * BATCH_STRIDE_
                       + (size_t)chunk * TCELLS_;
    for (int flat = tid * 4; flat < TFLOATS_; flat += 1024) {
        int c    = flat / TCELLS_;          // magic-mul, cheap
        int cell = flat - c * TCELLS_;      // 4-aligned, never crosses plane
        const float* src = tile + c * TSTRIDE_ + cell;
        vfloat4 v = {src[0], src[1], src[2], src[3]};
        __builtin_nontemporal_store(v, (vfloat4*)(obase + (size_t)c * PLANE_ + cell));
    }
}

extern "C" void kernel_launch(void* const* d_in, const int* in_sizes, int n_in,
                              void* d_out, int out_size, void* d_ws, size_t ws_size,
                              hipStream_t stream) {
    const float* pf0 = (const float*)d_in[0];
    const int*   co0 = (const int*)d_in[1];
    const float* pf1 = (const float*)d_in[2];
    const int*   co1 = (const int*)d_in[3];
    const float* pf2 = (const float*)d_in[4];
    const int*   co2 = (const int*)d_in[5];
    float* out = (float*)d_out;

    const int npil = in_sizes[1] / 4;   // rows in coords (B*P_PER)

    int* map = (int*)d_ws;
    const size_t map_bytes = 3 * MAP_BIN_ * sizeof(int);

    // init map to -1 (0xFFFFFFFF) — ~10 MB
    (void)hipMemsetAsync(map, 0xFF, map_bytes, stream);

    dim3 g1((npil + 255) / 256, 3, 1);
    scatter_idx_kernel<<<g1, 256, 0, stream>>>(co0, co1, co2, map, npil);

    dim3 g2(NCHUNK_, B_, 3);
    gather_lds_kernel<<<g2, 256, 0, stream>>>(pf0, pf1, pf2, map, out);
}

// Round 6
// 718.015 us; speedup vs baseline: 1.0313x; 1.0313x over previous
//
#include <hip/hip_runtime.h>

// Problem constants (match reference)
#define NX_ 432
#define NY_ 496
#define C_  64
#define B_  4
#define CELLS_ (NX_ * NY_)            // 214272 cells per (bin, batch) canvas plane
#define PLANE_ ((size_t)CELLS_)       // c-plane stride in floats
#define BATCH_STRIDE_ ((size_t)C_ * CELLS_)        // 13,713,408 floats
#define BIN_STRIDE_   ((size_t)B_ * C_ * CELLS_)   // 54,853,632 floats
#define MAP_BIN_ ((size_t)B_ * CELLS_)             // map entries per bin

#define SPLITS_ 48
#define SPAN_ (CELLS_ / SPLITS_)      // 4464 cells per block span (exact)

// native clang vector types — accepted by __builtin_nontemporal_store
typedef float vfloat4 __attribute__((ext_vector_type(4)));
typedef int   vint4   __attribute__((ext_vector_type(4)));

// ---------------------------------------------------------------------------
// Kernel 1: scatter pillar index p into map[bin][b*CELLS + z + y*NX + x]
// coords layout per row: [b, z, y, x] int32. Cells are unique per sample.
// ---------------------------------------------------------------------------
__global__ __launch_bounds__(256) void scatter_idx_kernel(
    const int* __restrict__ coords0,
    const int* __restrict__ coords1,
    const int* __restrict__ coords2,
    int* __restrict__ map, int npil)
{
    const int bin = blockIdx.y;
    const int p = blockIdx.x * 256 + threadIdx.x;
    if (p >= npil) return;
    const int* coords = (bin == 0) ? coords0 : (bin == 1) ? coords1 : coords2;
    vint4 c = ((const vint4*)coords)[p];
    size_t idx = (size_t)bin * MAP_BIN_ + (size_t)c.x * CELLS_ + c.y + c.z * NX_ + c.w;
    map[idx] = p;
}

// ---------------------------------------------------------------------------
// Kernel 2: dense gather. Block = (cell split of 4464, c-HALF of 32, bin, b).
// Per cell-iteration a thread owns 4 cells:
//   - int4 map load
//   - 8 c4-steps: 4 clamped dwordx4 row-segment loads (each thread walks its
//     4 pillars' 128B half-rows in 16B steps -> every fetched line fully
//     consumed by THIS block; read amplification x1, map x2 only)
//   - 4x4 register transpose, 4 nontemporal float4 stores
// Writes: per plane each block advances a sequential 17.8KB stream (the
// pattern R4 proved runs at ~5-6 TB/s). All VMEM is 16B ops (~83M total).
// ---------------------------------------------------------------------------
__global__ __launch_bounds__(256) void gather_kernel(
    const float* __restrict__ pf0,
    const float* __restrict__ pf1,
    const float* __restrict__ pf2,
    const int* __restrict__ map,
    float* __restrict__ out)
{
    const int split = blockIdx.x;        // 0..47
    const int half  = blockIdx.y;        // 0..1  (c in [half*32, half*32+32))
    const int bb    = blockIdx.z;        // 0..11 = bin*4 + b
    const int bin = bb >> 2;
    const int b   = bb & 3;

    const float* __restrict__ pf = (bin == 0) ? pf0 : (bin == 1) ? pf1 : pf2;
    const float* __restrict__ pfh = pf + half * 32;   // half-row base

    const int* mbase = map + (size_t)bin * MAP_BIN_ + (size_t)b * CELLS_
                           + (size_t)split * SPAN_;
    float* obase = out + (size_t)bin * BIN_STRIDE_ + (size_t)b * BATCH_STRIDE_
                       + (size_t)(half * 32) * PLANE_ + (size_t)split * SPAN_;

    for (int base = threadIdx.x * 4; base < SPAN_; base += 1024) {
        vint4 idx = *(const vint4*)(mbase + base);
        const bool v0 = idx.x >= 0, v1 = idx.y >= 0, v2 = idx.z >= 0, v3 = idx.w >= 0;

        // Clamp invalid to row 0 (always-safe address); 16B-aligned segment ptrs.
        const vfloat4* r0 = (const vfloat4*)(pfh + (size_t)(v0 ? idx.x : 0) * C_);
        const vfloat4* r1 = (const vfloat4*)(pfh + (size_t)(v1 ? idx.y : 0) * C_);
        const vfloat4* r2 = (const vfloat4*)(pfh + (size_t)(v2 ? idx.z : 0) * C_);
        const vfloat4* r3 = (const vfloat4*)(pfh + (size_t)(v3 ? idx.w : 0) * C_);

        float* o = obase + base;

        #pragma unroll 2
        for (int c4 = 0; c4 < 8; ++c4) {
            vfloat4 a0 = r0[c4];
            vfloat4 a1 = r1[c4];
            vfloat4 a2 = r2[c4];
            vfloat4 a3 = r3[c4];
            a0 = v0 ? a0 : (vfloat4)0.0f;
            a1 = v1 ? a1 : (vfloat4)0.0f;
            a2 = v2 ? a2 : (vfloat4)0.0f;
            a3 = v3 ? a3 : (vfloat4)0.0f;

            vfloat4 w0 = {a0.x, a1.x, a2.x, a3.x};
            vfloat4 w1 = {a0.y, a1.y, a2.y, a3.y};
            vfloat4 w2 = {a0.z, a1.z, a2.z, a3.z};
            vfloat4 w3 = {a0.w, a1.w, a2.w, a3.w};

            float* oc = o + (size_t)(c4 * 4) * PLANE_;
            __builtin_nontemporal_store(w0, (vfloat4*)(oc));
            __builtin_nontemporal_store(w1, (vfloat4*)(oc + PLANE_));
            __builtin_nontemporal_store(w2, (vfloat4*)(oc + 2 * PLANE_));
            __builtin_nontemporal_store(w3, (vfloat4*)(oc + 3 * PLANE_));
        }
    }
}

extern "C" void kernel_launch(void* const* d_in, const int* in_sizes, int n_in,
                              void* d_out, int out_size, void* d_ws, size_t ws_size,
                              hipStream_t stream) {
    const float* pf0 = (const float*)d_in[0];
    const int*   co0 = (const int*)d_in[1];
    const float* pf1 = (const float*)d_in[2];
    const int*   co1 = (const int*)d_in[3];
    const float* pf2 = (const float*)d_in[4];
    const int*   co2 = (const int*)d_in[5];
    float* out = (float*)d_out;

    const int npil = in_sizes[1] / 4;   // rows in coords (B*P_PER)

    int* map = (int*)d_ws;
    const size_t map_bytes = 3 * MAP_BIN_ * sizeof(int);

    // init map to -1 (0xFFFFFFFF) — ~10 MB
    (void)hipMemsetAsync(map, 0xFF, map_bytes, stream);

    dim3 g1((npil + 255) / 256, 3, 1);
    scatter_idx_kernel<<<g1, 256, 0, stream>>>(co0, co1, co2, map, npil);

    dim3 g2(SPLITS_, 2, 12);   // cell-splits x c-halves x (bin*B + b)
    gather_kernel<<<g2, 256, 0, stream>>>(pf0, pf1, pf2, map, out);
}